// Round 4
// baseline (90.100 us; speedup 1.0000x reference)
//
#include <hip/hip_runtime.h>
#include <math.h>

// Problem constants (match reference setup_inputs)
#define NN 4096
#define MM 128
#define QQ 64
#define DD 128
#define CC (MM * QQ)          // 8192 gemm "columns" (flattened m,q)
#define GRIDN 512             // persistent grid: 2 blocks/CU guaranteed resident

typedef float f32x4 __attribute__((ext_vector_type(4)));
typedef int   i32x4 __attribute__((ext_vector_type(4)));
typedef int   i32x8 __attribute__((ext_vector_type(8)));

#define AS1 __attribute__((address_space(1)))
#define AS3 __attribute__((address_space(3)))

// Self-resetting, fence-free grid barrier in device globals (zero-init at
// module load, NOT in the poisoned workspace -> no per-replay memset node).
// Counters are cumulative, never reset: a block derives its barrier instance
// from its own sub-counter ticket (prev>>6; 64 arrivals/sub/instance) and
// spins until master >= 8*(instance+1) (wrap-safe signed compare).
// Spin is RELAXED agent-scope (no per-poll cache invalidate); visibility of
// cross-phase data comes from bypass (agent-scope) stores + the vmcnt drain
// at __syncthreads -- the contract verified in rounds 2-3.
__device__ unsigned g_sub[8 * 16];   // 8 sub-counters, 64 B apart
__device__ unsigned g_master;

__device__ __forceinline__ void grid_barrier(int bid)
{
    __syncthreads();                       // drains vmcnt: stores are at MALL
    asm volatile("" ::: "memory");
    if (threadIdx.x == 0) {
        unsigned* sub = &g_sub[(bid & 7) * 16];
        const unsigned prev =
            __hip_atomic_fetch_add(sub, 1u, __ATOMIC_RELAXED, __HIP_MEMORY_SCOPE_AGENT);
        const unsigned tgt = ((prev >> 6) + 1u) << 3;   // 8*(instance+1)
        if ((prev & 63u) == 63u)
            __hip_atomic_fetch_add(&g_master, 1u, __ATOMIC_RELAXED, __HIP_MEMORY_SCOPE_AGENT);
        while ((int)(__hip_atomic_load(&g_master, __ATOMIC_RELAXED,
                                       __HIP_MEMORY_SCOPE_AGENT) - tgt) < 0)
            __builtin_amdgcn_s_sleep(8);
    }
    asm volatile("" ::: "memory");
    __syncthreads();
}

// Single kernel, single grid barrier:
//   phase B': per-block fused fp32->fp8 conversion + MX MFMA densities
//             (B-tile converted once; A-tiles reg-staged/converted, loads for
//              tile t4+1 issued before the MFMAs of tile t4 -> latency hidden)
//   barrier
//   phase C : normalize (verbatim from round 3)
__global__ __launch_bounds__(256, 2)
void kde_fused(const float* __restrict__ A, const float* __restrict__ B,
               const float* __restrict__ var,
               float* __restrict__ dpc,   // [MM][NN] transposed densities (ws)
               float* __restrict__ out)   // [NN][MM]
{
    __shared__ unsigned char Bs[128 * DD];        // 16 KB, converted once
    __shared__ unsigned char As[2][128 * DD];     // 32 KB, double-buffered
    __shared__ float a2s[2][128];
    __shared__ float b2s[128];

    const int bid = blockIdx.x;
    const int t = threadIdx.x, w = t >> 6, lane = t & 63;

    // bid bits: [2:0]=xcd, [5:3]=cb-within-xcd, [8:6]=nb0. cb constant across
    // the block's 4 tiles; B-tile shared by the 8 same-XCD nb0-blocks via L2.
    const int xcd = bid & 7;
    const int cb  = (xcd << 3) | ((bid >> 3) & 7);   // 0..63
    const int nb0 = bid >> 6;                        // 0..7
    const int c0  = cb * 128;

    // ---- conversion mapping: thread owns a half-row (64 fp32 = 4 fp8 chunks)
    const int rr = t >> 1, hh = t & 1;
    float4 vv[16];                                   // in-flight fp32 half-row

    // issue the 16 coalescing-friendly float4 loads of a 128x128 fp32 tile
    auto load_tile = [&](const float* __restrict__ src) {
        const float4* s4 = (const float4*)src;
        const int base = (rr << 5) + (hh << 4);
        #pragma unroll
        for (int f = 0; f < 16; ++f) vv[f] = s4[base + f];
    };
    // convert vv -> fp8 into the XOR-swizzled LDS layout + exact fp32 row norm
    auto convert_tile = [&](unsigned char* __restrict__ dst, float* __restrict__ nrm) {
        float s = 0.f;
        #pragma unroll
        for (int i = 0; i < 4; ++i) {
            i32x4 wvv;
            #pragma unroll
            for (int k = 0; k < 4; ++k) {
                const float4 v = vv[i * 4 + k];
                s += v.x * v.x + v.y * v.y + v.z * v.z + v.w * v.w;
                int pk = __builtin_amdgcn_cvt_pk_fp8_f32(v.x, v.y, 0, false);  // bytes 0,1
                pk     = __builtin_amdgcn_cvt_pk_fp8_f32(v.z, v.w, pk, true);  // bytes 2,3
                wvv[k] = pk;
            }
            const int c16 = (hh << 2) | i;           // logical 16B chunk 0..7
            *(i32x4*)&dst[((rr << 3) | (c16 ^ (rr & 7))) << 4] = wvv;
        }
        s += __shfl_xor(s, 1, 64);                   // pair (2u,2u+1): full row
        if (hh == 0) nrm[rr] = s;
    };

    // ---- prologue: convert B-tile and A-tile 0 ----
    load_tile(B + (size_t)c0 * DD);
    convert_tile(Bs, b2s);
    load_tile(A + (size_t)(nb0 * 128) * DD);
    convert_tile(As[0], a2s[0]);
    __syncthreads();

    const int l15 = lane & 15, q = lane >> 4, xr = l15 & 7;
    const int wy = w >> 1, wx = w & 1;
    const int rbase = wy * 64, cbase = wx * 64;
    const int m = (cb << 1) + wx;
    const float hinv = 0.5f / var[0];
    const float h2   = hinv + hinv;

    // hoist c-side factors: c = cbase + jc*16 + q*4 + r
    f32x4 nbh[4];
    #pragma unroll
    for (int jc = 0; jc < 4; ++jc) {
        const f32x4 bv = *(const f32x4*)&b2s[cbase + jc * 16 + q * 4];
        nbh[jc] = -bv * hinv;
    }

    #pragma unroll
    for (int t4 = 0; t4 < 4; ++t4) {
        const int buf = t4 & 1;
        const int n0  = (nb0 + 8 * t4) * 128;

        // issue next A-tile's fp32 loads now; consumed after the epilogue
        if (t4 < 3)
            load_tile(A + (size_t)((nb0 + 8 * (t4 + 1)) * 128) * DD);

        // A fragments: lane holds A[rbase+i*16+l15][q*32 .. q*32+31]
        i32x8 a8[4];
        #pragma unroll
        for (int i = 0; i < 4; ++i) {
            const int ro = (rbase + i * 16 + l15) * DD;
            const i32x4 lo = *(const i32x4*)&As[buf][ro + (((q << 1) | 0) ^ xr) * 16];
            const i32x4 hi = *(const i32x4*)&As[buf][ro + (((q << 1) | 1) ^ xr) * 16];
            #pragma unroll
            for (int e = 0; e < 4; ++e) { a8[i][e] = lo[e]; a8[i][4 + e] = hi[e]; }
        }

        // Swapped operands: D[row=c][col=n] -> c-reduction is in-register.
        f32x4 acc[4][4] = {};
        __builtin_amdgcn_s_setprio(1);
        #pragma unroll
        for (int jc = 0; jc < 4; ++jc) {
            const int ro = (cbase + jc * 16 + l15) * DD;
            const i32x4 lo = *(const i32x4*)&Bs[ro + (((q << 1) | 0) ^ xr) * 16];
            const i32x4 hi = *(const i32x4*)&Bs[ro + (((q << 1) | 1) ^ xr) * 16];
            i32x8 b8;
            #pragma unroll
            for (int e = 0; e < 4; ++e) { b8[e] = lo[e]; b8[4 + e] = hi[e]; }
            #pragma unroll
            for (int i = 0; i < 4; ++i)
                acc[jc][i] = __builtin_amdgcn_mfma_scale_f32_16x16x128_f8f6f4(
                                b8, a8[i], acc[jc][i],
                                0, 0,          // cbsz=0 (fp8), blgp=0 (fp8)
                                0, 127,        // scale_a = 1.0
                                0, 127);       // scale_b = 1.0
        }
        __builtin_amdgcn_s_setprio(0);

        // epilogue: dens = exp((2ab - a2 - b2) * 0.5/var); 16 c lane-local
        // (15 adds) + 4-way over q (2 shfl_xor).
        float sums[4];
        #pragma unroll
        for (int i = 0; i < 4; ++i) {
            const float aih = a2s[buf][rbase + i * 16 + l15] * hinv;
            float s = 0.f;
            #pragma unroll
            for (int jc = 0; jc < 4; ++jc)
                #pragma unroll
                for (int r = 0; r < 4; ++r)
                    s += __expf(fmaf(h2, acc[jc][i][r], nbh[jc][r] - aih));
            s += __shfl_xor(s, 16, 64);
            s += __shfl_xor(s, 32, 64);
            sums[i] = s;   // full 64-col sum for n = rbase + i*16 + l15
        }
        // lane writes its own n = rbase + lane (i == q); static select
        const float v01 = (q & 1) ? sums[1] : sums[0];
        const float v23 = (q & 1) ? sums[3] : sums[2];
        const float myv = (q & 2) ? v23 : v01;
        __hip_atomic_store(&dpc[(size_t)m * NN + n0 + rbase + lane], myv,
                           __ATOMIC_RELAXED, __HIP_MEMORY_SCOPE_AGENT);

        // convert the prefetched tile into the other buffer (no one reads it
        // this iteration; previous readers were separated by last iter's sync)
        if (t4 < 3)
            convert_tile(As[buf ^ 1], a2s[buf ^ 1]);
        __syncthreads();
    }

    grid_barrier(bid);

    // ---------------- Phase C: normalize, 8 n per block ----------------
    {
        const int n0c = bid * 8;
        float* tile = (float*)&As[0][0];   // reuse: [128][9] floats, padded
        float* rden = b2s;                 // reuse: 8 floats
        const int mr = t >> 1, half = t & 1;
        const float4 v = *(const float4*)&dpc[(size_t)mr * NN + n0c + half * 4];
        float* tr = &tile[mr * 9 + half * 4];
        tr[0] = v.x; tr[1] = v.y; tr[2] = v.z; tr[3] = v.w;
        __syncthreads();
        if (t < 8) {
            float s = 0.f;
            #pragma unroll 8
            for (int mm = 0; mm < MM; ++mm) s += tile[mm * 9 + t];  // m ascending
            rden[t] = 1.f / (s + 1e-10f);
        }
        __syncthreads();
        const int j = t >> 5, mq = (t & 31) * 4;
        const float r = rden[j];
        float4 o;
        o.x = tile[(mq + 0) * 9 + j] * r;
        o.y = tile[(mq + 1) * 9 + j] * r;
        o.z = tile[(mq + 2) * 9 + j] * r;
        o.w = tile[(mq + 3) * 9 + j] * r;
        *(float4*)&out[(size_t)(n0c + j) * MM + mq] = o;   // coalesced
    }
}

extern "C" void kernel_launch(void* const* d_in, const int* in_sizes, int n_in,
                              void* d_out, int out_size, void* d_ws, size_t ws_size,
                              hipStream_t stream) {
    const float* A   = (const float*)d_in[0];   // [4096][128]
    const float* B   = (const float*)d_in[1];   // [128][64][128] = [8192][128]
    const float* var = (const float*)d_in[2];   // [1]
    float* out = (float*)d_out;                 // [4096][128]

    float* dpc = (float*)d_ws;                  // 2 MB, [MM][NN] (poison-filled
                                                // each iter -> clears stale L2)

    // single graph node: no memset (barrier counters are self-resetting
    // device globals), no prep kernel, no norm kernel
    kde_fused<<<GRIDN, 256, 0, stream>>>(A, B, var, dpc, out);
}

// Round 5
// 82.065 us; speedup vs baseline: 1.0979x; 1.0979x over previous
//
#include <hip/hip_runtime.h>
#include <math.h>

// Problem constants (match reference setup_inputs)
#define NN 4096
#define MM 128
#define QQ 64
#define DD 128
#define CC (MM * QQ)          // 8192 gemm "columns" (flattened m,q)
#define GRIDN 512             // persistent grid: 2 blocks/CU guaranteed resident

typedef float f32x4 __attribute__((ext_vector_type(4)));
typedef int   i32x4 __attribute__((ext_vector_type(4)));
typedef int   i32x8 __attribute__((ext_vector_type(8)));

#define AS1 __attribute__((address_space(1)))
#define AS3 __attribute__((address_space(3)))

// Self-resetting, fence-free grid barrier in device globals (zero-init at
// module load, NOT in the poisoned workspace -> no per-replay memset node).
// Counters are cumulative, never reset: a block derives its barrier instance
// from its own sub-counter ticket (prev>>6; 64 arrivals/sub/instance) and
// spins until master >= 8*(instance+1) (wrap-safe signed compare).
// Spin is RELAXED agent-scope (no per-poll cache invalidate); visibility of
// cross-phase data comes from bypass (agent-scope) stores + the vmcnt drain
// at __syncthreads -- contract verified in rounds 2-4.
__device__ unsigned g_sub[8 * 16];   // 8 sub-counters, 64 B apart
__device__ unsigned g_master;

__device__ __forceinline__ void grid_barrier(int bid)
{
    __syncthreads();                       // drains vmcnt: stores are at MALL
    asm volatile("" ::: "memory");
    if (threadIdx.x == 0) {
        unsigned* sub = &g_sub[(bid & 7) * 16];
        const unsigned prev =
            __hip_atomic_fetch_add(sub, 1u, __ATOMIC_RELAXED, __HIP_MEMORY_SCOPE_AGENT);
        const unsigned tgt = ((prev >> 6) + 1u) << 3;   // 8*(instance+1)
        if ((prev & 63u) == 63u)
            __hip_atomic_fetch_add(&g_master, 1u, __ATOMIC_RELAXED, __HIP_MEMORY_SCOPE_AGENT);
        while ((int)(__hip_atomic_load(&g_master, __ATOMIC_RELAXED,
                                       __HIP_MEMORY_SCOPE_AGENT) - tgt) < 0)
            __builtin_amdgcn_s_sleep(8);
    }
    asm volatile("" ::: "memory");
    __syncthreads();
}

// One persistent kernel: phase A (fp32->fp8 + norms, bypass-stored, done ONCE
// -- round-4 lesson: fusing conversion into consumers multiplies it by the
// 64x A-tile reuse factor), phase B (fp8 MX MFMA densities; swapped operands
// put the c-reduction in-register), phase C (normalize).
__global__ __launch_bounds__(256, 2)
void kde_fused(const float* __restrict__ A, const float* __restrict__ B,
               const float* __restrict__ var,
               unsigned char* __restrict__ A8, unsigned char* __restrict__ B8,
               float* __restrict__ a2w, float* __restrict__ b2w,
               float* __restrict__ dpc,   // [MM][NN] transposed densities (ws)
               float* __restrict__ out)   // [NN][MM]
{
    __shared__ unsigned char Bs[128 * DD];        // 16 KB, staged once per block
    __shared__ unsigned char As[2][128 * DD];     // 32 KB, double-buffered
    __shared__ float a2s[2][128];
    __shared__ float b2s[128];

    const int bid = blockIdx.x;
    const int t = threadIdx.x, w = t >> 6, lane = t & 63;

    // ---------------- Phase A: convert + exact fp32 squared norms ----------------
    // Outputs written with agent-scope bypass stores (visibility without fences).
    {
        const int l32 = t & 31;
        #pragma unroll
        for (int p = 0; p < 3; ++p) {
            const int row = bid * 24 + p * 8 + (t >> 5);   // 512*24 = 12288 rows
            const float* src; unsigned char* dst; float* nrm;
            if (row < NN) { src = A + (size_t)row * DD; dst = A8 + (size_t)row * DD; nrm = a2w + row; }
            else {
                const int r = row - NN;
                src = B + (size_t)r * DD; dst = B8 + (size_t)r * DD; nrm = b2w + r;
            }
            const float4 v = ((const float4*)src)[l32];
            int pk = __builtin_amdgcn_cvt_pk_fp8_f32(v.x, v.y, 0, false);   // bytes 0,1
            pk     = __builtin_amdgcn_cvt_pk_fp8_f32(v.z, v.w, pk, true);   // bytes 2,3
            __hip_atomic_store((unsigned int*)dst + l32, (unsigned int)pk,
                               __ATOMIC_RELAXED, __HIP_MEMORY_SCOPE_AGENT);
            float s = v.x * v.x + v.y * v.y + v.z * v.z + v.w * v.w;
            #pragma unroll
            for (int mth = 16; mth > 0; mth >>= 1) s += __shfl_xor(s, mth, 64);  // 32-group
            if (l32 == 0)
                __hip_atomic_store(nrm, s, __ATOMIC_RELAXED, __HIP_MEMORY_SCOPE_AGENT);
        }
    }

    grid_barrier(bid);

    // ---------------- Phase B: densities (4 tiles/block, fixed cb) ----------------
    {
        // bid bits: [2:0]=xcd, [5:3]=cb-within-xcd, [8:6]=nb0. cb constant across
        // the block's 4 tiles -> B staged once; nb = nb0 + 8*t4 covers all 32.
        const int xcd = bid & 7;
        const int cb  = (xcd << 3) | ((bid >> 3) & 7);   // 0..63
        const int nb0 = bid >> 6;                        // 0..7
        const int c0  = cb * 128;

        // stage B (once) + b2s + As[0] + a2s[0]
        {
            const unsigned char* Bb = B8 + (size_t)c0 * DD;
            #pragma unroll
            for (int i = 0; i < 4; ++i) {
                const int slot = w * 256 + i * 64 + lane;            // 0..1023
                const int r = slot >> 3, c16 = slot & 7, scb = c16 ^ (r & 7);
                __builtin_amdgcn_global_load_lds(
                    (const AS1 unsigned int*)(Bb + r * DD + scb * 16),
                    (AS3 unsigned int*)&Bs[slot * 16], 16, 0, 0);
            }
            if (w >= 2)
                __builtin_amdgcn_global_load_lds(
                    (const AS1 unsigned int*)(b2w + c0 + (w - 2) * 64 + lane),
                    (AS3 unsigned int*)&b2s[(w - 2) * 64 + lane], 4, 0, 0);
            const int n0 = nb0 * 128;
            const unsigned char* Ab = A8 + (size_t)n0 * DD;
            #pragma unroll
            for (int i = 0; i < 4; ++i) {
                const int slot = w * 256 + i * 64 + lane;
                const int r = slot >> 3, c16 = slot & 7, scb = c16 ^ (r & 7);
                __builtin_amdgcn_global_load_lds(
                    (const AS1 unsigned int*)(Ab + r * DD + scb * 16),
                    (AS3 unsigned int*)&As[0][slot * 16], 16, 0, 0);
            }
            if (w < 2)
                __builtin_amdgcn_global_load_lds(
                    (const AS1 unsigned int*)(a2w + n0 + w * 64 + lane),
                    (AS3 unsigned int*)&a2s[0][w * 64 + lane], 4, 0, 0);
        }
        __syncthreads();   // drains vmcnt(0) incl. global_load_lds

        const int l15 = lane & 15, q = lane >> 4, xr = l15 & 7;
        const int wy = w >> 1, wx = w & 1;
        const int rbase = wy * 64, cbase = wx * 64;
        const int m = (cb << 1) + wx;
        const float hinv = 0.5f / var[0];
        const float h2   = hinv + hinv;

        // hoist c-side factors out of the t4 loop: c = cbase + jc*16 + q*4 + r
        f32x4 nbh[4];
        #pragma unroll
        for (int jc = 0; jc < 4; ++jc) {
            const f32x4 bv = *(const f32x4*)&b2s[cbase + jc * 16 + q * 4];
            nbh[jc] = -bv * hinv;
        }

        #pragma unroll
        for (int t4 = 0; t4 < 4; ++t4) {
            const int buf = t4 & 1;
            const int n0  = (nb0 + 8 * t4) * 128;

            // prefetch next A-tile into the other buffer (hidden under MFMA)
            if (t4 < 3) {
                const int n0n = (nb0 + 8 * (t4 + 1)) * 128;
                const unsigned char* Ab = A8 + (size_t)n0n * DD;
                #pragma unroll
                for (int i = 0; i < 4; ++i) {
                    const int slot = w * 256 + i * 64 + lane;
                    const int r = slot >> 3, c16 = slot & 7, scb = c16 ^ (r & 7);
                    __builtin_amdgcn_global_load_lds(
                        (const AS1 unsigned int*)(Ab + r * DD + scb * 16),
                        (AS3 unsigned int*)&As[buf ^ 1][slot * 16], 16, 0, 0);
                }
                if (w < 2)
                    __builtin_amdgcn_global_load_lds(
                        (const AS1 unsigned int*)(a2w + n0n + w * 64 + lane),
                        (AS3 unsigned int*)&a2s[buf ^ 1][w * 64 + lane], 4, 0, 0);
            }

            // A fragments: lane holds A[rbase+i*16+l15][q*32 .. q*32+31]
            i32x8 a8[4];
            #pragma unroll
            for (int i = 0; i < 4; ++i) {
                const int ro = (rbase + i * 16 + l15) * DD;
                const i32x4 lo = *(const i32x4*)&As[buf][ro + (((q << 1) | 0) ^ xr) * 16];
                const i32x4 hi = *(const i32x4*)&As[buf][ro + (((q << 1) | 1) ^ xr) * 16];
                #pragma unroll
                for (int e = 0; e < 4; ++e) { a8[i][e] = lo[e]; a8[i][4 + e] = hi[e]; }
            }

            // Swapped operands: D[row=c][col=n] -> c-reduction is in-register.
            // acc[jc][i][r] = <A_n, B_c> for n = rbase+i*16+l15, c = cbase+jc*16+q*4+r
            f32x4 acc[4][4] = {};
            __builtin_amdgcn_s_setprio(1);
            #pragma unroll
            for (int jc = 0; jc < 4; ++jc) {
                const int ro = (cbase + jc * 16 + l15) * DD;
                const i32x4 lo = *(const i32x4*)&Bs[ro + (((q << 1) | 0) ^ xr) * 16];
                const i32x4 hi = *(const i32x4*)&Bs[ro + (((q << 1) | 1) ^ xr) * 16];
                i32x8 b8;
                #pragma unroll
                for (int e = 0; e < 4; ++e) { b8[e] = lo[e]; b8[4 + e] = hi[e]; }
                #pragma unroll
                for (int i = 0; i < 4; ++i)
                    acc[jc][i] = __builtin_amdgcn_mfma_scale_f32_16x16x128_f8f6f4(
                                    b8, a8[i], acc[jc][i],
                                    0, 0,          // cbsz=0 (fp8), blgp=0 (fp8)
                                    0, 127,        // scale_a = 1.0
                                    0, 127);       // scale_b = 1.0
            }
            __builtin_amdgcn_s_setprio(0);

            // epilogue: dens = exp((2ab - a2 - b2) * 0.5/var); 16 c lane-local
            // -> 2 independent partial chains (add-ILP) + 4-way over q (2 shfl).
            float sums[4];
            #pragma unroll
            for (int i = 0; i < 4; ++i) {
                const float aih = a2s[buf][rbase + i * 16 + l15] * hinv;
                float s0 = 0.f, s1 = 0.f;
                #pragma unroll
                for (int jc = 0; jc < 4; jc += 2) {
                    #pragma unroll
                    for (int r = 0; r < 4; ++r) {
                        s0 += __expf(fmaf(h2, acc[jc][i][r],     nbh[jc][r]     - aih));
                        s1 += __expf(fmaf(h2, acc[jc + 1][i][r], nbh[jc + 1][r] - aih));
                    }
                }
                float s = s0 + s1;
                s += __shfl_xor(s, 16, 64);
                s += __shfl_xor(s, 32, 64);
                sums[i] = s;   // full 64-col sum for n = rbase + i*16 + l15
            }
            // lane writes its own n = rbase + lane (i == q); static select
            const float v01 = (q & 1) ? sums[1] : sums[0];
            const float v23 = (q & 1) ? sums[3] : sums[2];
            const float myv = (q & 2) ? v23 : v01;
            __hip_atomic_store(&dpc[(size_t)m * NN + n0 + rbase + lane], myv,
                               __ATOMIC_RELAXED, __HIP_MEMORY_SCOPE_AGENT);
            __syncthreads();   // As[buf^1] ready; As[buf]/a2s[buf] reads done
        }
    }

    grid_barrier(bid);

    // ---------------- Phase C: normalize, 8 n per block ----------------
    {
        const int n0c = bid * 8;
        float* tile = (float*)&As[0][0];   // reuse: [128][9] floats, padded
        float* rden = b2s;                 // reuse: 8 floats
        const int mr = t >> 1, half = t & 1;
        const float4 v = *(const float4*)&dpc[(size_t)mr * NN + n0c + half * 4];
        float* tr = &tile[mr * 9 + half * 4];
        tr[0] = v.x; tr[1] = v.y; tr[2] = v.z; tr[3] = v.w;
        __syncthreads();
        if (t < 8) {
            float s = 0.f;
            #pragma unroll 8
            for (int mm = 0; mm < MM; ++mm) s += tile[mm * 9 + t];  // m ascending
            rden[t] = 1.f / (s + 1e-10f);
        }
        __syncthreads();
        const int j = t >> 5, mq = (t & 31) * 4;
        const float r = rden[j];
        float4 o;
        o.x = tile[(mq + 0) * 9 + j] * r;
        o.y = tile[(mq + 1) * 9 + j] * r;
        o.z = tile[(mq + 2) * 9 + j] * r;
        o.w = tile[(mq + 3) * 9 + j] * r;
        *(float4*)&out[(size_t)(n0c + j) * MM + mq] = o;   // coalesced
    }
}

extern "C" void kernel_launch(void* const* d_in, const int* in_sizes, int n_in,
                              void* d_out, int out_size, void* d_ws, size_t ws_size,
                              hipStream_t stream) {
    const float* A   = (const float*)d_in[0];   // [4096][128]
    const float* B   = (const float*)d_in[1];   // [128][64][128] = [8192][128]
    const float* var = (const float*)d_in[2];   // [1]
    float* out = (float*)d_out;                 // [4096][128]

    unsigned char* A8 = (unsigned char*)d_ws;            // 512 KB
    unsigned char* B8 = A8 + (size_t)NN * DD;            // 1 MB
    float* a2  = (float*)(B8 + (size_t)CC * DD);         // 16 KB
    float* b2  = a2 + NN;                                // 32 KB
    float* dpc = b2 + CC;                                // 2 MB, [MM][NN]

    // single graph node: barrier counters are self-resetting device globals
    kde_fused<<<GRIDN, 256, 0, stream>>>(A, B, var, A8, B8, a2, b2, dpc, out);
}

// Round 7
// 78.374 us; speedup vs baseline: 1.1496x; 1.0471x over previous
//
#include <hip/hip_runtime.h>
#include <math.h>

// Problem constants (match reference setup_inputs)
#define NN 4096
#define MM 128
#define QQ 64
#define DD 128
#define CC (MM * QQ)          // 8192 gemm "columns" (flattened m,q)
#define GRIDN 512             // persistent grid: 2 blocks/CU guaranteed resident

typedef float f32x4 __attribute__((ext_vector_type(4)));
typedef int   i32x4 __attribute__((ext_vector_type(4)));
typedef int   i32x8 __attribute__((ext_vector_type(8)));

#define AS1 __attribute__((address_space(1)))
#define AS3 __attribute__((address_space(3)))

// Self-resetting, fence-free grid barrier in device globals (zero-init at
// module load). Cumulative counters: block derives its barrier instance from
// its sub-counter ticket (prev>>6) and spins until master >= 8*(instance+1).
// RELAXED agent-scope ops (coherence from scope, no per-poll invalidates);
// cross-phase visibility = bypass stores + vmcnt drain at __syncthreads.
// Contract verified rounds 2-5.
__device__ unsigned g_sub[8 * 16];   // 8 sub-counters, 64 B apart
__device__ unsigned g_master;

__device__ __forceinline__ void grid_barrier(int bid)
{
    __syncthreads();                       // drains vmcnt: stores are at MALL
    asm volatile("" ::: "memory");
    if (threadIdx.x == 0) {
        unsigned* sub = &g_sub[(bid & 7) * 16];
        const unsigned prev =
            __hip_atomic_fetch_add(sub, 1u, __ATOMIC_RELAXED, __HIP_MEMORY_SCOPE_AGENT);
        const unsigned tgt = ((prev >> 6) + 1u) << 3;   // 8*(instance+1)
        if ((prev & 63u) == 63u)
            __hip_atomic_fetch_add(&g_master, 1u, __ATOMIC_RELAXED, __HIP_MEMORY_SCOPE_AGENT);
        while ((int)(__hip_atomic_load(&g_master, __ATOMIC_RELAXED,
                                       __HIP_MEMORY_SCOPE_AGENT) - tgt) < 0)
            __builtin_amdgcn_s_sleep(8);
    }
    asm volatile("" ::: "memory");
    __syncthreads();
}

// Phase A (fp32->fp8 + norms, once), barrier, phase B (MX MFMA densities:
// B-fragments hoisted out of the t4 loop; dpc stores deferred to after the
// loop so per-t4 syncthreads drains only the early-issued prefetch), barrier,
// phase C (normalize).
__global__ __launch_bounds__(256, 2)
void kde_fused(const float* __restrict__ A, const float* __restrict__ B,
               const float* __restrict__ var,
               unsigned char* __restrict__ A8, unsigned char* __restrict__ B8,
               float* __restrict__ a2w, float* __restrict__ b2w,
               float* __restrict__ dpc,   // [MM][NN] transposed densities (ws)
               float* __restrict__ out)   // [NN][MM]
{
    __shared__ unsigned char Bs[128 * DD];        // 16 KB, staged once per block
    __shared__ unsigned char As[2][128 * DD];     // 32 KB, double-buffered
    __shared__ float a2s[2][128];
    __shared__ float b2s[128];
    // pad LDS past 160/3 KB so at most 2 blocks fit per CU -> dispatcher
    // places exactly 2 everywhere (uniform block timing under grid barriers;
    // without this, 3-block CUs straggle while other CUs sit empty).
    // Kept alive by a single volatile store (valid in host+device passes).
    __shared__ unsigned char lds_pad[4096];

    const int bid = blockIdx.x;
    const int t = threadIdx.x, w = t >> 6, lane = t & 63;

    if (t == 0) { volatile unsigned char* p = lds_pad; p[0] = 0; }

    // ---------------- Phase A: convert + exact fp32 squared norms ----------------
    {
        const int l32 = t & 31;
        #pragma unroll
        for (int p = 0; p < 3; ++p) {
            const int row = bid * 24 + p * 8 + (t >> 5);   // 512*24 = 12288 rows
            const float* src; unsigned char* dst; float* nrm;
            if (row < NN) { src = A + (size_t)row * DD; dst = A8 + (size_t)row * DD; nrm = a2w + row; }
            else {
                const int r = row - NN;
                src = B + (size_t)r * DD; dst = B8 + (size_t)r * DD; nrm = b2w + r;
            }
            const float4 v = ((const float4*)src)[l32];
            int pk = __builtin_amdgcn_cvt_pk_fp8_f32(v.x, v.y, 0, false);   // bytes 0,1
            pk     = __builtin_amdgcn_cvt_pk_fp8_f32(v.z, v.w, pk, true);   // bytes 2,3
            __hip_atomic_store((unsigned int*)dst + l32, (unsigned int)pk,
                               __ATOMIC_RELAXED, __HIP_MEMORY_SCOPE_AGENT);
            float s = v.x * v.x + v.y * v.y + v.z * v.z + v.w * v.w;
            #pragma unroll
            for (int mth = 16; mth > 0; mth >>= 1) s += __shfl_xor(s, mth, 64);  // 32-group
            if (l32 == 0)
                __hip_atomic_store(nrm, s, __ATOMIC_RELAXED, __HIP_MEMORY_SCOPE_AGENT);
        }
    }

    grid_barrier(bid);

    // ---------------- Phase B: densities (4 tiles/block, fixed cb) ----------------
    const int xcd = bid & 7;
    const int cb  = (xcd << 3) | ((bid >> 3) & 7);   // 0..63
    const int nb0 = bid >> 6;                        // 0..7
    const int c0  = cb * 128;
    {
        // stage B (once) + b2s + As[0] + a2s[0]
        {
            const unsigned char* Bb = B8 + (size_t)c0 * DD;
            #pragma unroll
            for (int i = 0; i < 4; ++i) {
                const int slot = w * 256 + i * 64 + lane;            // 0..1023
                const int r = slot >> 3, c16 = slot & 7, scb = c16 ^ (r & 7);
                __builtin_amdgcn_global_load_lds(
                    (const AS1 unsigned int*)(Bb + r * DD + scb * 16),
                    (AS3 unsigned int*)&Bs[slot * 16], 16, 0, 0);
            }
            if (w >= 2)
                __builtin_amdgcn_global_load_lds(
                    (const AS1 unsigned int*)(b2w + c0 + (w - 2) * 64 + lane),
                    (AS3 unsigned int*)&b2s[(w - 2) * 64 + lane], 4, 0, 0);
            const int n0 = nb0 * 128;
            const unsigned char* Ab = A8 + (size_t)n0 * DD;
            #pragma unroll
            for (int i = 0; i < 4; ++i) {
                const int slot = w * 256 + i * 64 + lane;
                const int r = slot >> 3, c16 = slot & 7, scb = c16 ^ (r & 7);
                __builtin_amdgcn_global_load_lds(
                    (const AS1 unsigned int*)(Ab + r * DD + scb * 16),
                    (AS3 unsigned int*)&As[0][slot * 16], 16, 0, 0);
            }
            if (w < 2)
                __builtin_amdgcn_global_load_lds(
                    (const AS1 unsigned int*)(a2w + n0 + w * 64 + lane),
                    (AS3 unsigned int*)&a2s[0][w * 64 + lane], 4, 0, 0);
        }
        __syncthreads();   // drains vmcnt(0) incl. global_load_lds

        const int l15 = lane & 15, q = lane >> 4, xr = l15 & 7;
        const int wy = w >> 1, wx = w & 1;
        const int rbase = wy * 64, cbase = wx * 64;
        const int m = (cb << 1) + wx;
        const float hinvL = (0.5f / var[0]) * 1.44269504088896f;  // 0.5/var * log2(e)
        const float h2L   = hinvL + hinvL;

        // hoist c-side factors AND B-fragments out of the t4 loop (Bs is
        // immutable after the prologue; these were re-read every iteration)
        f32x4 nbh[4];
        i32x8 b8v[4];
        #pragma unroll
        for (int jc = 0; jc < 4; ++jc) {
            const f32x4 bv = *(const f32x4*)&b2s[cbase + jc * 16 + q * 4];
            nbh[jc] = -bv * hinvL;
            const int ro = (cbase + jc * 16 + l15) * DD;
            const i32x4 lo = *(const i32x4*)&Bs[ro + (((q << 1) | 0) ^ xr) * 16];
            const i32x4 hi = *(const i32x4*)&Bs[ro + (((q << 1) | 1) ^ xr) * 16];
            #pragma unroll
            for (int e = 0; e < 4; ++e) { b8v[jc][e] = lo[e]; b8v[jc][4 + e] = hi[e]; }
        }

        float myv[4];   // deferred dpc values (statically indexed)

        #pragma unroll
        for (int t4 = 0; t4 < 4; ++t4) {
            const int buf = t4 & 1;

            // prefetch next A-tile into the other buffer (hidden under MFMA)
            if (t4 < 3) {
                const int n0n = (nb0 + 8 * (t4 + 1)) * 128;
                const unsigned char* Ab = A8 + (size_t)n0n * DD;
                #pragma unroll
                for (int i = 0; i < 4; ++i) {
                    const int slot = w * 256 + i * 64 + lane;
                    const int r = slot >> 3, c16 = slot & 7, scb = c16 ^ (r & 7);
                    __builtin_amdgcn_global_load_lds(
                        (const AS1 unsigned int*)(Ab + r * DD + scb * 16),
                        (AS3 unsigned int*)&As[buf ^ 1][slot * 16], 16, 0, 0);
                }
                if (w < 2)
                    __builtin_amdgcn_global_load_lds(
                        (const AS1 unsigned int*)(a2w + n0n + w * 64 + lane),
                        (AS3 unsigned int*)&a2s[buf ^ 1][w * 64 + lane], 4, 0, 0);
            }

            // A fragments: lane holds A[rbase+i*16+l15][q*32 .. q*32+31]
            i32x8 a8[4];
            #pragma unroll
            for (int i = 0; i < 4; ++i) {
                const int ro = (rbase + i * 16 + l15) * DD;
                const i32x4 lo = *(const i32x4*)&As[buf][ro + (((q << 1) | 0) ^ xr) * 16];
                const i32x4 hi = *(const i32x4*)&As[buf][ro + (((q << 1) | 1) ^ xr) * 16];
                #pragma unroll
                for (int e = 0; e < 4; ++e) { a8[i][e] = lo[e]; a8[i][4 + e] = hi[e]; }
            }

            // Swapped operands: D[row=c][col=n] -> c-reduction is in-register.
            // Pure-register MFMA cluster (16 MFMAs, no ds ops interleaved).
            f32x4 acc[4][4] = {};
            __builtin_amdgcn_s_setprio(1);
            #pragma unroll
            for (int jc = 0; jc < 4; ++jc)
                #pragma unroll
                for (int i = 0; i < 4; ++i)
                    acc[jc][i] = __builtin_amdgcn_mfma_scale_f32_16x16x128_f8f6f4(
                                    b8v[jc], a8[i], acc[jc][i],
                                    0, 0,          // cbsz=0 (fp8), blgp=0 (fp8)
                                    0, 127,        // scale_a = 1.0
                                    0, 127);       // scale_b = 1.0
            __builtin_amdgcn_s_setprio(0);

            // epilogue: dens = exp2(log2e*(2ab - a2 - b2)*0.5/var);
            // 16 c lane-local -> 2 partial chains + 4-way over q (2 shfl).
            float sums[4];
            #pragma unroll
            for (int i = 0; i < 4; ++i) {
                const float aih = a2s[buf][rbase + i * 16 + l15] * hinvL;
                float s0 = 0.f, s1 = 0.f;
                #pragma unroll
                for (int jc = 0; jc < 4; jc += 2) {
                    #pragma unroll
                    for (int r = 0; r < 4; ++r) {
                        s0 += __builtin_amdgcn_exp2f(fmaf(h2L, acc[jc][i][r],     nbh[jc][r]     - aih));
                        s1 += __builtin_amdgcn_exp2f(fmaf(h2L, acc[jc + 1][i][r], nbh[jc + 1][r] - aih));
                    }
                }
                float s = s0 + s1;
                s += __shfl_xor(s, 16, 64);
                s += __shfl_xor(s, 32, 64);
                sums[i] = s;   // full 64-col sum for n = rbase + i*16 + l15
            }
            // lane owns n = rbase + lane (i == q); static select, store deferred
            const float v01 = (q & 1) ? sums[1] : sums[0];
            const float v23 = (q & 1) ? sums[3] : sums[2];
            myv[t4] = (q & 2) ? v23 : v01;

            __syncthreads();   // As[buf^1] ready; As[buf]/a2s[buf] reads done
        }

        // deferred dpc stores: drained by barrier-2's syncthreads (one drain
        // total instead of one per t4 iteration)
        #pragma unroll
        for (int t4 = 0; t4 < 4; ++t4) {
            const int n0 = (nb0 + 8 * t4) * 128;
            __hip_atomic_store(&dpc[(size_t)m * NN + n0 + rbase + lane], myv[t4],
                               __ATOMIC_RELAXED, __HIP_MEMORY_SCOPE_AGENT);
        }
    }

    grid_barrier(bid);

    // ---------------- Phase C: normalize, 8 n per block ----------------
    {
        const int n0c = bid * 8;
        float* tile = (float*)&As[0][0];   // reuse: [128][9] floats, padded
        float* rden = b2s;                 // reuse: 8 floats
        const int mr = t >> 1, half = t & 1;
        const float4 v = *(const float4*)&dpc[(size_t)mr * NN + n0c + half * 4];
        float* tr = &tile[mr * 9 + half * 4];
        tr[0] = v.x; tr[1] = v.y; tr[2] = v.z; tr[3] = v.w;
        __syncthreads();
        if (t < 8) {
            float s = 0.f;
            #pragma unroll 8
            for (int mm = 0; mm < MM; ++mm) s += tile[mm * 9 + t];  // m ascending
            rden[t] = 1.f / (s + 1e-10f);
        }
        __syncthreads();
        const int j = t >> 5, mq = (t & 31) * 4;
        const float r = rden[j];
        float4 o;
        o.x = tile[(mq + 0) * 9 + j] * r;
        o.y = tile[(mq + 1) * 9 + j] * r;
        o.z = tile[(mq + 2) * 9 + j] * r;
        o.w = tile[(mq + 3) * 9 + j] * r;
        *(float4*)&out[(size_t)(n0c + j) * MM + mq] = o;   // coalesced
    }
}

extern "C" void kernel_launch(void* const* d_in, const int* in_sizes, int n_in,
                              void* d_out, int out_size, void* d_ws, size_t ws_size,
                              hipStream_t stream) {
    const float* A   = (const float*)d_in[0];   // [4096][128]
    const float* B   = (const float*)d_in[1];   // [128][64][128] = [8192][128]
    const float* var = (const float*)d_in[2];   // [1]
    float* out = (float*)d_out;                 // [4096][128]

    unsigned char* A8 = (unsigned char*)d_ws;            // 512 KB
    unsigned char* B8 = A8 + (size_t)NN * DD;            // 1 MB
    float* a2  = (float*)(B8 + (size_t)CC * DD);         // 16 KB
    float* b2  = a2 + NN;                                // 32 KB
    float* dpc = b2 + CC;                                // 2 MB, [MM][NN]

    // single graph node: barrier counters are self-resetting device globals
    kde_fused<<<GRIDN, 256, 0, stream>>>(A, B, var, A8, B8, a2, b2, dpc, out);
}